// Round 6
// baseline (85.933 us; speedup 1.0000x reference)
//
#include <hip/hip_runtime.h>
#include <hip/hip_bf16.h>
#include <stdint.h>

// Batched NT-GEMM: out[b,i,j] = sum_d m1[b,i,d] * m2[b,j,d]
// B=16, M=N=2048, K=256, fp32 in/out; f16 MFMA compute.
//
// Round 6: persistent 4-tile blocks, unified 32-step pipeline.
//  - grid 1024; each block owns 4 consecutive-bcol tiles (same A panel).
//  - One flat s=0..31 K-step pipeline (tile = s>>3, kt = s&7) with the X/Y
//    2-deep register prefetch crossing tile boundaries.
//  - Tile-i epilogue stores are issued mid-kernel right after its last MFMA;
//    next tile's loads are already in flight BEFORE the stores (vmcnt is
//    in-order, so load-waits never drain stores). Store drain overlaps
//    tile-(i+1) compute. Only the block-final drain is exposed (2/CU vs 8).
//  - acc WAR hazard (VMEM stores read VGPRs async): re-zero acc one full
//    staging phase after store issue, pinned by sched_barrier(0).

typedef _Float16 f16x8 __attribute__((ext_vector_type(8)));
typedef _Float16 f16x4 __attribute__((ext_vector_type(4)));
typedef _Float16 f16x2 __attribute__((ext_vector_type(2)));
typedef float f32x4 __attribute__((ext_vector_type(4)));

#define NB 16
#define DM 2048
#define DN 2048
#define DK 256
#define BM 128
#define BN 128
#define BK 32
#define BKP 36                 // padded LDS row stride (elements)
#define NT 8                   // K-steps per tile
#define NTILES 4               // output tiles per block (consecutive bcol)
#define TSTEPS (NT * NTILES)   // 32 pipeline steps
#define NWG 1024               // 16 b * 16 brow * 4 col-groups

__global__ __launch_bounds__(256, 2) void fused_gemm(const float* __restrict__ A,
                                                     const float* __restrict__ B,
                                                     float* __restrict__ C) {
    __shared__ _Float16 As[2][BM * BKP];   // 9216 B per buffer
    __shared__ _Float16 Bs[2][BN * BKP];

    const int t = threadIdx.x;

    // XCD swizzle (1024 % 8 == 0 -> bijective). Each XCD gets 128 consecutive
    // swz = 2 whole batches; within: grp fastest -> 4 blocks share an A panel,
    // B panel working set 2 MB fits the 4 MB XCD L2 across brow advance.
    const int bid = blockIdx.x;
    const int swz = (bid & 7) * (NWG / 8) + (bid >> 3);
    const int b    = swz >> 6;            // 64 blocks per batch
    const int rem  = swz & 63;
    const int brow = (rem >> 2) << 7;     // * BM
    const int grp  = rem & 3;             // col-group: bcol = grp*512 + tile*128

    const float* At  = A + (size_t)b * DM * DK + (size_t)brow * DK;
    const float* Bt0 = B + (size_t)b * DN * DK + (size_t)(grp << 9) * DK;

    const int w    = t >> 6;
    const int l    = t & 63;
    const int wr   = (w >> 1) * 64;       // wave row offset in tile
    const int wc   = (w & 1) * 64;        // wave col offset in tile
    const int lrow = l & 15;
    const int lko  = (l >> 4) * 8;        // k-offset of lane's 8 f16 elements

    f32x4 acc[4][4] = {};

    // Staging: tile-step = 128 rows x 32 k fp32 = 1024 float4 chunks;
    // thread t owns chunks c = t + i*256 -> row r = c>>3, quad q = c&7.
    auto issue = [&](int s, float4 (&va)[4], float4 (&vb)[4]) {
        const float* Ap = At + (size_t)(s & 7) * BK;
        const float* Bp = Bt0 + (size_t)(s >> 3) * BM * DK + (size_t)(s & 7) * BK;
#pragma unroll
        for (int i = 0; i < 4; ++i) {
            const int c = t + i * 256;
            const int r = c >> 3, q = c & 7;
            va[i] = *reinterpret_cast<const float4*>(Ap + (size_t)r * DK + q * 4);
            vb[i] = *reinterpret_cast<const float4*>(Bp + (size_t)r * DK + q * 4);
        }
    };
    auto wlds = [&](int buf, const float4 (&va)[4], const float4 (&vb)[4]) {
#pragma unroll
        for (int i = 0; i < 4; ++i) {
            const int c = t + i * 256;
            const int r = c >> 3, q = c & 7;
            f16x2 alo = __builtin_bit_cast(f16x2, __builtin_amdgcn_cvt_pkrtz(va[i].x, va[i].y));
            f16x2 ahi = __builtin_bit_cast(f16x2, __builtin_amdgcn_cvt_pkrtz(va[i].z, va[i].w));
            f16x2 blo = __builtin_bit_cast(f16x2, __builtin_amdgcn_cvt_pkrtz(vb[i].x, vb[i].y));
            f16x2 bhi = __builtin_bit_cast(f16x2, __builtin_amdgcn_cvt_pkrtz(vb[i].z, vb[i].w));
            f16x4 ha = { alo[0], alo[1], ahi[0], ahi[1] };
            f16x4 hb = { blo[0], blo[1], bhi[0], bhi[1] };
            *reinterpret_cast<f16x4*>(&As[buf][r * BKP + q * 4]) = ha;
            *reinterpret_cast<f16x4*>(&Bs[buf][r * BKP + q * 4]) = hb;
        }
    };
    auto compute = [&](int buf) {
        f16x8 af[4], bfr[4];
#pragma unroll
        for (int m = 0; m < 4; ++m)
            af[m] = *reinterpret_cast<const f16x8*>(&As[buf][(wr + m * 16 + lrow) * BKP + lko]);
#pragma unroll
        for (int n = 0; n < 4; ++n)
            bfr[n] = *reinterpret_cast<const f16x8*>(&Bs[buf][(wc + n * 16 + lrow) * BKP + lko]);
#pragma unroll
        for (int m = 0; m < 4; ++m)
#pragma unroll
            for (int n = 0; n < 4; ++n)
                acc[m][n] = __builtin_amdgcn_mfma_f32_16x16x32_f16(af[m], bfr[n], acc[m][n], 0, 0, 0);
    };

    // Epilogue stores for one tile. C/D layout: col=lane&15, row=(lane>>4)*4+reg.
    float* Cb = C + (size_t)b * DM * DN;
    const int crow0 = brow + wr + (l >> 4) * 4;
    const int ccol0 = (grp << 9) + wc + lrow;
    auto store_tile = [&](int tile) {
        const int ccol = ccol0 + tile * BN;
#pragma unroll
        for (int m = 0; m < 4; ++m)
#pragma unroll
            for (int j = 0; j < 4; ++j) {
                float* rowp = Cb + (size_t)(crow0 + m * 16 + j) * DN + ccol;
#pragma unroll
                for (int n = 0; n < 4; ++n)
                    __builtin_nontemporal_store(acc[m][n][j], rowp + n * 16);
            }
    };

    // Two named in-flight register sets (static indexing only - rule #20).
    float4 vaX[4], vbX[4], vaY[4], vbY[4];

    // Prologue: steps 0 (X) and 1 (Y) in flight; write step 0 -> buf0.
    issue(0, vaX, vbX);
    issue(1, vaY, vbY);
    wlds(0, vaX, vbX);        // counted wait: Y's 8 loads stay outstanding
    __syncthreads();

    // Flat 32-step pipeline, 2 steps per iteration (buf0 then buf1).
#pragma unroll 1
    for (int s2 = 0; s2 < TSTEPS; s2 += 2) {
        if (s2 + 2 < TSTEPS) issue(s2 + 2, vaX, vbX);

        // Tile boundary passed 1 iteration ago: acc was stored at s2-2 (end);
        // re-zero here, ~a full staging phase after store issue (WAR on store
        // data regs -> compiler inserts counted vmcnt; L2 acks are done by now).
        if (s2 > 0 && (s2 & 7) == 0) {
#pragma unroll
            for (int m = 0; m < 4; ++m)
#pragma unroll
                for (int n = 0; n < 4; ++n) acc[m][n] = f32x4{0.f, 0.f, 0.f, 0.f};
        }

        compute(0);
        wlds(1, vaY, vbY);
        __syncthreads();

        if (s2 + 3 < TSTEPS) issue(s2 + 3, vaY, vbY);
        compute(1);

        if ((s2 & 7) == 6) {
            // Steps s2+1 = 7,15,23,31: tile (s2+1)>>3 is complete. Store it.
            // The next tile's first loads (s2+2 -> X) are ALREADY in flight,
            // issued before these stores, so their wait won't drain stores.
            store_tile((s2 + 1) >> 3);
            __builtin_amdgcn_sched_barrier(0);   // pin: nothing moves above stores
        }

        if (s2 + 2 < TSTEPS) wlds(0, vaX, vbX);
        __syncthreads();
    }
}

extern "C" void kernel_launch(void* const* d_in, const int* in_sizes, int n_in,
                              void* d_out, int out_size, void* d_ws, size_t ws_size,
                              hipStream_t stream) {
    const float* m1 = (const float*)d_in[0];
    const float* m2 = (const float*)d_in[1];
    float* out = (float*)d_out;
    (void)d_ws; (void)ws_size;

    fused_gemm<<<NWG, 256, 0, stream>>>(m1, m2, out);
}

// Round 7
// 75.779 us; speedup vs baseline: 1.1340x; 1.1340x over previous
//
#include <hip/hip_runtime.h>
#include <hip/hip_bf16.h>
#include <stdint.h>

// Batched NT-GEMM: out[b,i,j] = sum_d m1[b,i,d] * m2[b,j,d]
// B=16, M=N=2048, K=256, fp32 in/out; f16 MFMA compute.
//
// Round 7 = round 5 (75.8us) + ONE change: raw s_barrier with counted vmcnt.
//   __syncthreads() forces `s_waitcnt vmcnt(0)` before s_barrier (m97 finding),
//   draining the X/Y prefetch loads issued ~300cy earlier -> per-K-step stall.
//   Replaced with: `s_waitcnt lgkmcnt(0)` (publish LDS writes) + s_barrier,
//   memory-clobber fenced (rule #18 / m201 template). Global loads now stay
//   in flight across barriers; vmcnt waits are dependency-counted (16), never 0.

typedef _Float16 f16x8 __attribute__((ext_vector_type(8)));
typedef _Float16 f16x4 __attribute__((ext_vector_type(4)));
typedef _Float16 f16x2 __attribute__((ext_vector_type(2)));
typedef float f32x4 __attribute__((ext_vector_type(4)));

#define NB 16
#define DM 2048
#define DN 2048
#define DK 256
#define BM 128
#define BN 128
#define BK 32
#define BKP 36                          // padded LDS row stride (elements)
#define NT (DK / BK)                    // 8 K-steps
#define NWG (NB * (DM/BM) * (DN/BN))    // 4096 blocks

// lgkm-only barrier: LDS writes published, VMEM loads stay outstanding.
#define LDS_BARRIER() do {                                   \
    asm volatile("s_waitcnt lgkmcnt(0)" ::: "memory");       \
    __builtin_amdgcn_s_barrier();                            \
    asm volatile("" ::: "memory");                           \
} while (0)

__global__ __launch_bounds__(256, 2) void fused_gemm(const float* __restrict__ A,
                                                     const float* __restrict__ B,
                                                     float* __restrict__ C) {
    __shared__ _Float16 As[2][BM * BKP];   // 9216 B per buffer
    __shared__ _Float16 Bs[2][BN * BKP];

    const int t = threadIdx.x;

    // XCD swizzle (NWG % 8 == 0 -> bijective). XCD k gets a contiguous chunk;
    // within a chunk bx is fastest (per-batch panels ~4MB ~ one XCD L2).
    const int bid = blockIdx.x;
    const int swz = (bid & 7) * (NWG / 8) + (bid >> 3);
    const int b    = swz >> 8;          // 256 blocks per batch
    const int rem  = swz & 255;
    const int brow = (rem >> 4) << 7;   // * BM
    const int bcol = (rem & 15) << 7;   // * BN

    const float* At = A + (size_t)b * DM * DK + (size_t)brow * DK;
    const float* Bt = B + (size_t)b * DN * DK + (size_t)bcol * DK;

    const int w    = t >> 6;
    const int l    = t & 63;
    const int wr   = (w >> 1) * 64;     // wave row offset in tile
    const int wc   = (w & 1) * 64;      // wave col offset in tile
    const int lrow = l & 15;
    const int lko  = (l >> 4) * 8;      // k-offset of lane's 8 f16 elements

    f32x4 acc[4][4] = {};

    // Staging geometry: tile = 128 rows x 32 k fp32 = 1024 float4 chunks;
    // thread t owns chunks c = t + i*256 -> row r = c>>3, quad q = c&7.
    auto issue = [&](int kt, float4 (&va)[4], float4 (&vb)[4]) {
#pragma unroll
        for (int i = 0; i < 4; ++i) {
            const int c = t + i * 256;
            const int r = c >> 3, q = c & 7;
            va[i] = *reinterpret_cast<const float4*>(At + (size_t)r * DK + kt * BK + q * 4);
            vb[i] = *reinterpret_cast<const float4*>(Bt + (size_t)r * DK + kt * BK + q * 4);
        }
    };
    auto wlds = [&](int buf, const float4 (&va)[4], const float4 (&vb)[4]) {
#pragma unroll
        for (int i = 0; i < 4; ++i) {
            const int c = t + i * 256;
            const int r = c >> 3, q = c & 7;
            f16x2 alo = __builtin_bit_cast(f16x2, __builtin_amdgcn_cvt_pkrtz(va[i].x, va[i].y));
            f16x2 ahi = __builtin_bit_cast(f16x2, __builtin_amdgcn_cvt_pkrtz(va[i].z, va[i].w));
            f16x2 blo = __builtin_bit_cast(f16x2, __builtin_amdgcn_cvt_pkrtz(vb[i].x, vb[i].y));
            f16x2 bhi = __builtin_bit_cast(f16x2, __builtin_amdgcn_cvt_pkrtz(vb[i].z, vb[i].w));
            f16x4 ha = { alo[0], alo[1], ahi[0], ahi[1] };
            f16x4 hb = { blo[0], blo[1], bhi[0], bhi[1] };
            *reinterpret_cast<f16x4*>(&As[buf][r * BKP + q * 4]) = ha;
            *reinterpret_cast<f16x4*>(&Bs[buf][r * BKP + q * 4]) = hb;
        }
    };
    auto compute = [&](int buf) {
        f16x8 af[4], bfr[4];
#pragma unroll
        for (int m = 0; m < 4; ++m)
            af[m] = *reinterpret_cast<const f16x8*>(&As[buf][(wr + m * 16 + lrow) * BKP + lko]);
#pragma unroll
        for (int n = 0; n < 4; ++n)
            bfr[n] = *reinterpret_cast<const f16x8*>(&Bs[buf][(wc + n * 16 + lrow) * BKP + lko]);
#pragma unroll
        for (int m = 0; m < 4; ++m)
#pragma unroll
            for (int n = 0; n < 4; ++n)
                acc[m][n] = __builtin_amdgcn_mfma_f32_16x16x32_f16(af[m], bfr[n], acc[m][n], 0, 0, 0);
    };

    // Two named in-flight register sets (static indexing only - rule #20).
    float4 vaX[4], vbX[4], vaY[4], vbY[4];

    // Prologue: tiles 0 (X) and 1 (Y) in flight; write tile 0 -> buf0.
    issue(0, vaX, vbX);
    issue(1, vaY, vbY);
    wlds(0, vaX, vbX);        // vmcnt(16): Y's loads stay outstanding
    LDS_BARRIER();

    // Steady state, manually unrolled x2 (roles X/Y alternate; buf = kt&1).
#pragma unroll
    for (int k2 = 0; k2 < NT; k2 += 2) {
        if (k2 + 2 < NT) issue(k2 + 2, vaX, vbX);
        compute(0);
        wlds(1, vaY, vbY);                 // vmcnt(16): X stays in flight
        LDS_BARRIER();

        if (k2 + 3 < NT) issue(k2 + 3, vaY, vbY);
        compute(1);
        if (k2 + 2 < NT) {
            wlds(0, vaX, vbX);             // vmcnt(16): Y stays in flight
        }
        LDS_BARRIER();
    }

    // Epilogue. C/D layout (m89/m91): col = lane&15, row = (lane>>4)*4 + reg.
    float* Cb = C + (size_t)b * DM * DN;
    const int crow = brow + wr + (l >> 4) * 4;
    const int ccol = bcol + wc + lrow;
#pragma unroll
    for (int m = 0; m < 4; ++m)
#pragma unroll
        for (int j = 0; j < 4; ++j) {
            float* rowp = Cb + (size_t)(crow + m * 16 + j) * DN + ccol;
#pragma unroll
            for (int n = 0; n < 4; ++n)
                __builtin_nontemporal_store(acc[m][n][j], rowp + n * 16);
        }
}

extern "C" void kernel_launch(void* const* d_in, const int* in_sizes, int n_in,
                              void* d_out, int out_size, void* d_ws, size_t ws_size,
                              hipStream_t stream) {
    const float* m1 = (const float*)d_in[0];
    const float* m2 = (const float*)d_in[1];
    float* out = (float*)d_out;
    (void)d_ws; (void)ws_size;

    fused_gemm<<<NWG, 256, 0, stream>>>(m1, m2, out);
}